// Round 22
// baseline (593.734 us; speedup 1.0000x reference)
//
#include <hip/hip_runtime.h>
#include <hip/hip_cooperative_groups.h>
#include <math.h>

namespace cg = cooperative_groups;

#define B_ 16
#define T_ 1024
#define D_ 96
#define L_ 6
#define NH_ 6
#define HS_ 16
#define FF_ 384

typedef _Float16 h4 __attribute__((ext_vector_type(4)));
typedef _Float16 h8 __attribute__((ext_vector_type(8)));
typedef __fp16 g2 __attribute__((ext_vector_type(2)));
typedef __fp16 g4 __attribute__((ext_vector_type(4)));
typedef float f4 __attribute__((ext_vector_type(4)));

#define MFMA16 __builtin_amdgcn_mfma_f32_16x16x16f16

// packed f16 weights, layout [frag][stp][lane 0..63][8 halves]
#define OFF_GO   0
#define OFF_QKV  9216
#define OFF_PROJ 175104
#define OFF_FF1  230400
#define OFF_FF2  451584
#define OFF_ACT  672768
#define PACK_TOTAL 674304

// Q weights pre-scaled by 1/sqrt(16) * log2(e) so attn uses exp2 directly.
#define QSCALE 0.3606737602222409f

static __device__ __forceinline__ h4 pk4(const float* p) {
  g2 lo = __builtin_amdgcn_cvt_pkrtz(p[0], p[1]);
  g2 hi = __builtin_amdgcn_cvt_pkrtz(p[2], p[3]);
  g4 r4 = __builtin_shufflevector(lo, hi, 0, 1, 2, 3);
  return __builtin_bit_cast(h4, r4);
}

static __device__ __forceinline__ void ldpair(const _Float16* base, int blk,
                                              int lane, h4& a, h4& b) {
  h8 t = *(const h8*)(base + (size_t)blk * 512 + lane * 8);
  a = __builtin_shufflevector(t, t, 0, 1, 2, 3);
  b = __builtin_shufflevector(t, t, 4, 5, 6, 7);
}

static __device__ __forceinline__ void ldkv(const _Float16* kB_, const _Float16* vB_,
                                            int tile, int lane,
                                            h4& k0, h4& k1, h4& v0, h4& v1) {
  h8 kt = *(const h8*)(kB_ + (size_t)tile * 512 + lane * 8);
  k0 = __builtin_shufflevector(kt, kt, 0, 1, 2, 3);
  k1 = __builtin_shufflevector(kt, kt, 4, 5, 6, 7);
  h8 vt = *(const h8*)(vB_ + (size_t)tile * 512 + lane * 8);
  v0 = __builtin_shufflevector(vt, vt, 0, 1, 2, 3);
  v1 = __builtin_shufflevector(vt, vt, 4, 5, 6, 7);
}

static __device__ __forceinline__ void astep_full(
    const h4& kc0, const h4& kc1, const h4& vc0, const h4& vc1,
    const h4& qf0, const h4& qf1, const h4& ones,
    f4& O0, f4& O1, f4& S0, f4& S1) {
  const f4 zero4 = {0.f, 0.f, 0.f, 0.f};
  f4 sa0 = MFMA16(kc0, qf0, zero4, 0, 0, 0);
  f4 sa1 = MFMA16(kc1, qf0, zero4, 0, 0, 0);
  f4 sb0 = MFMA16(kc0, qf1, zero4, 0, 0, 0);
  f4 sb1 = MFMA16(kc1, qf1, zero4, 0, 0, 0);
  float pa0[4], pa1[4], pb0[4], pb1[4];
#pragma unroll
  for (int r = 0; r < 4; ++r) {
    pa0[r] = __builtin_amdgcn_exp2f(sa0[r]);
    pa1[r] = __builtin_amdgcn_exp2f(sa1[r]);
    pb0[r] = __builtin_amdgcn_exp2f(sb0[r]);
    pb1[r] = __builtin_amdgcn_exp2f(sb1[r]);
  }
  h4 fa0 = pk4(pa0), fa1 = pk4(pa1), fb0 = pk4(pb0), fb1 = pk4(pb1);
  O0 = MFMA16(fa0, vc0, O0, 0, 0, 0);
  O0 = MFMA16(fa1, vc1, O0, 0, 0, 0);
  S0 = MFMA16(fa0, ones, S0, 0, 0, 0);
  S0 = MFMA16(fa1, ones, S0, 0, 0, 0);
  O1 = MFMA16(fb0, vc0, O1, 0, 0, 0);
  O1 = MFMA16(fb1, vc1, O1, 0, 0, 0);
  S1 = MFMA16(fb0, ones, S1, 0, 0, 0);
  S1 = MFMA16(fb1, ones, S1, 0, 0, 0);
}

static __device__ __forceinline__ void astep_diag(
    const h4& kc0, const h4& kc1, const h4& vc0, const h4& vc1,
    const h4& qf0, const h4& qf1, const h4& ones,
    f4& O0, f4& O1, f4& S0, f4& S1, int lr, int lg) {
  const f4 zero4 = {0.f, 0.f, 0.f, 0.f};
  f4 sa0 = MFMA16(kc0, qf0, zero4, 0, 0, 0);
  float pa0[4];
#pragma unroll
  for (int r = 0; r < 4; ++r)
    pa0[r] = (lg * 4 + r <= lr) ? __builtin_amdgcn_exp2f(sa0[r]) : 0.f;
  h4 fa0 = pk4(pa0);
  O0 = MFMA16(fa0, vc0, O0, 0, 0, 0);
  S0 = MFMA16(fa0, ones, S0, 0, 0, 0);
  f4 sb0 = MFMA16(kc0, qf1, zero4, 0, 0, 0);
  f4 sb1 = MFMA16(kc1, qf1, zero4, 0, 0, 0);
  float pb0[4], pb1[4];
#pragma unroll
  for (int r = 0; r < 4; ++r) {
    pb0[r] = __builtin_amdgcn_exp2f(sb0[r]);
    pb1[r] = (lg * 4 + r <= lr) ? __builtin_amdgcn_exp2f(sb1[r]) : 0.f;
  }
  h4 fb0 = pk4(pb0), fb1 = pk4(pb1);
  O1 = MFMA16(fb0, vc0, O1, 0, 0, 0);
  O1 = MFMA16(fb1, vc1, O1, 0, 0, 0);
  S1 = MFMA16(fb0, ones, S1, 0, 0, 0);
  S1 = MFMA16(fb1, ones, S1, 0, 0, 0);
}

// ---------- pack all weights into paired-fragment layout ----------
__global__ __launch_bounds__(256) void pack_all_kernel(
    const float* __restrict__ w_go, const float* __restrict__ wq,
    const float* __restrict__ wk, const float* __restrict__ wv,
    const float* __restrict__ w_proj, const float* __restrict__ w_ff1,
    const float* __restrict__ w_ff2, const float* __restrict__ w_act,
    _Float16* __restrict__ P) {
  int i = blockIdx.x * 256 + threadIdx.x;
  if (i >= PACK_TOTAL) return;
  float v;
  if (i < OFF_QKV) {                       // GO: 6 frags, 3 stp
    int o = i, nf = o / 1536, r = o % 1536, stp = r / 512, q = r & 511;
    int lane = q >> 3, h8i = q & 7, lr = lane & 15, lg = lane >> 4;
    int st = stp * 2 + (h8i >> 2), j = h8i & 3;
    int n = nf * 16 + lr, k = st * 16 + lg * 4 + j;
    v = w_go[k * 96 + n];
  } else if (i < OFF_PROJ) {               // QKV: per layer 18 frags, 3 stp
    int o = i - OFF_QKV, l = o / 27648, r0 = o % 27648;
    int nf = r0 / 1536, r = r0 % 1536, stp = r / 512, q = r & 511;
    int lane = q >> 3, h8i = q & 7, lr = lane & 15, lg = lane >> 4;
    int st = stp * 2 + (h8i >> 2), j = h8i & 3;
    int c = nf * 16 + lr, k = st * 16 + lg * 4 + j;
    int which = c / 96, hc = c % 96, h = hc >> 4, jx = hc & 15;
    const float* s = (which == 0) ? wq : (which == 1 ? wk : wv);
    v = s[((l * NH_ + h) * 96 + k) * 16 + jx];
    if (which == 0) v *= QSCALE;
  } else if (i < OFF_FF1) {                // PROJ: per layer 6 frags, 3 stp
    int o = i - OFF_PROJ, l = o / 9216, r0 = o % 9216;
    int nf = r0 / 1536, r = r0 % 1536, stp = r / 512, q = r & 511;
    int lane = q >> 3, h8i = q & 7, lr = lane & 15, lg = lane >> 4;
    int st = stp * 2 + (h8i >> 2), j = h8i & 3;
    int n = nf * 16 + lr, k = st * 16 + lg * 4 + j;
    v = w_proj[l * 9216 + k * 96 + n];
  } else if (i < OFF_FF2) {                // FF1: per layer 24 frags, 3 stp
    int o = i - OFF_FF1, l = o / 36864, r0 = o % 36864;
    int nf = r0 / 1536, r = r0 % 1536, stp = r / 512, q = r & 511;
    int lane = q >> 3, h8i = q & 7, lr = lane & 15, lg = lane >> 4;
    int st = stp * 2 + (h8i >> 2), j = h8i & 3;
    int n = nf * 16 + lr, k = st * 16 + lg * 4 + j;
    v = w_ff1[l * 36864 + k * 384 + n];
  } else if (i < OFF_ACT) {                // FF2: per layer 6 frags, 12 stp
    int o = i - OFF_FF2, l = o / 36864, r0 = o % 36864;
    int nf = r0 / 6144, r = r0 % 6144, stp = r / 512, q = r & 511;
    int lane = q >> 3, h8i = q & 7, lr = lane & 15, lg = lane >> 4;
    int st = stp * 2 + (h8i >> 2), j = h8i & 3;
    int n = nf * 16 + lr, k = st * 16 + lg * 4 + j;
    v = w_ff2[l * 36864 + k * 96 + n];
  } else {                                 // ACT: 1 frag, 3 stp
    int o = i - OFF_ACT, stp = o / 512, q = o & 511;
    int lane = q >> 3, h8i = q & 7, lr = lane & 15, lg = lane >> 4;
    int st = stp * 2 + (h8i >> 2), j = h8i & 3;
    int k = st * 16 + lg * 4 + j;
    v = w_act[k * 16 + lr];
  }
  P[i] = (_Float16)v;
}

// ---------- embed kernel: concat+embed+pos -> x; LN1+qkv -> QKV[0] ----------
__global__ __launch_bounds__(384, 1) void embed_kernel(
    const float* __restrict__ goals, const float* __restrict__ obss,
    const float* __restrict__ pos, const float* __restrict__ b_go,
    const _Float16* __restrict__ Wp, float* __restrict__ x,
    const float* __restrict__ lntg, const float* __restrict__ lntb,
    const _Float16* __restrict__ Wtail,
    _Float16* __restrict__ qp_, _Float16* __restrict__ kp_,
    _Float16* __restrict__ vp_) {
  __shared__ float smemf[16128];
#define XSH(g, row, c) ((_Float16*)smemf + (size_t)(g) * 1920 + (row) * 20 + (c))
#define LNS(g, w, r, i) smemf[15360 + (((g) * 6 + (w)) * 16 + (r)) * 2 + (i)]
#define XP(g) (x + ((size_t)(blockIdx.x * 4 + (g)) * 6 + cfo) * 256 + lane * 4)
  const int tid = threadIdx.x;
  const int wave = tid >> 6, lane = tid & 63;
  const int lr = lane & 15, lg = lane >> 4;
  const int b = blockIdx.x >> 4, jj = blockIdx.x & 15;
  const int cfo = wave;
  const f4 zero4 = {0.f, 0.f, 0.f, 0.f};
  int mrow[4] = {2 * jj, 2 * jj + 1, 62 - 2 * jj, 63 - 2 * jj};
  int tt_[4], t2_[4];
#pragma unroll
  for (int g = 0; g < 4; ++g) { tt_[g] = mrow[g] * 16 + lr; t2_[g] = (g < 2) ? jj : 31 - jj; }

  f4 xc[4];
  h4 ef[4][6];
#pragma unroll
  for (int st = 0; st < 2; ++st) {
    f4 s4 = *(const f4*)(goals + b * 32 + st * 16 + lg * 4);
    h4 e = (h4){(_Float16)s4[0], (_Float16)s4[1], (_Float16)s4[2], (_Float16)s4[3]};
#pragma unroll
    for (int g = 0; g < 4; ++g) ef[g][st] = e;
  }
#pragma unroll
  for (int g = 0; g < 4; ++g)
#pragma unroll
    for (int st = 2; st < 6; ++st) {
      f4 s4 = *(const f4*)(obss + (size_t)(b * 1024 + tt_[g]) * 64 +
                           (st - 2) * 16 + lg * 4);
      ef[g][st] = (h4){(_Float16)s4[0], (_Float16)s4[1], (_Float16)s4[2], (_Float16)s4[3]};
    }
  h4 wf[6];
#pragma unroll
  for (int stp = 0; stp < 3; ++stp)
    ldpair(Wp, cfo * 3 + stp, lane, wf[2 * stp], wf[2 * stp + 1]);
  f4 bb = *(const f4*)(b_go + cfo * 16 + lg * 4);
#pragma unroll
  for (int g = 0; g < 4; ++g) {
    f4 a = zero4;
#pragma unroll
    for (int st = 0; st < 6; ++st) a = MFMA16(wf[st], ef[g][st], a, 0, 0, 0);
    f4 pp = *(const f4*)(pos + (size_t)tt_[g] * 96 + cfo * 16 + lg * 4);
#pragma unroll
    for (int j = 0; j < 4; ++j) xc[g][j] = a[j] + bb[j] + pp[j];
    *(f4*)XP(g) = xc[g];
  }

#pragma unroll
  for (int g = 0; g < 4; ++g) {
    float s = xc[g][0] + xc[g][1] + xc[g][2] + xc[g][3];
    float sq = xc[g][0] * xc[g][0] + xc[g][1] * xc[g][1] +
               xc[g][2] * xc[g][2] + xc[g][3] * xc[g][3];
    s += __shfl_xor(s, 16); sq += __shfl_xor(sq, 16);
    s += __shfl_xor(s, 32); sq += __shfl_xor(sq, 32);
    if (lane < 16) { LNS(g, wave, lr, 0) = s; LNS(g, wave, lr, 1) = sq; }
  }
  __syncthreads();
  {
    f4 gg4 = *(const f4*)(lntg + cfo * 16 + lg * 4);
    f4 b4 = *(const f4*)(lntb + cfo * 16 + lg * 4);
#pragma unroll
    for (int g = 0; g < 4; ++g) {
      float s = 0.f, sq = 0.f;
#pragma unroll
      for (int w = 0; w < 6; ++w) { s += LNS(g, w, lr, 0); sq += LNS(g, w, lr, 1); }
      float mean = s * (1.f / 96.f);
      float rs = rsqrtf(sq * (1.f / 96.f) - mean * mean + 1e-5f);
      h4 xn;
#pragma unroll
      for (int j = 0; j < 4; ++j)
        xn[j] = (_Float16)((xc[g][j] - mean) * rs * gg4[j] + b4[j]);
      *(h4*)XSH(g, cfo * 16 + lr, lg * 4) = xn;
    }
  }
  __syncthreads();
  h4 xf[4][6];
#pragma unroll
  for (int g = 0; g < 4; ++g)
#pragma unroll
    for (int st = 0; st < 6; ++st)
      xf[g][st] = *(const h4*)XSH(g, st * 16 + lr, lg * 4);
#pragma unroll
  for (int f = 0; f < 3; ++f) {
    int nf = wave * 3 + f;
    h4 wt[6];
#pragma unroll
    for (int stp = 0; stp < 3; ++stp)
      ldpair(Wtail, nf * 3 + stp, lane, wt[2 * stp], wt[2 * stp + 1]);
#pragma unroll
    for (int g = 0; g < 4; ++g) {
      f4 a = zero4;
#pragma unroll
      for (int st = 0; st < 6; ++st) a = MFMA16(wt[st], xf[g][st], a, 0, 0, 0);
      if (nf < 12) {
        int h = nf < 6 ? nf : nf - 6;
        _Float16* dst = (nf < 6 ? qp_ : kp_) +
                        ((size_t)(b * NH_ + h) * 32 + t2_[g]) * 512 +
                        lane * 8 + (g & 1) * 4;
        h4 hv = {(_Float16)a[0], (_Float16)a[1], (_Float16)a[2], (_Float16)a[3]};
        *(h4*)dst = hv;
      } else {
        int hb = nf - 12;
        _Float16* vbase = vp_ + ((size_t)(b * NH_ + hb) * 32 + t2_[g]) * 512;
        int jb = (lr & 3) + (g & 1) * 4;
        int lgp = lr >> 2;
#pragma unroll
        for (int r = 0; r < 4; ++r)
          vbase[(lgp * 16 + lg * 4 + r) * 8 + jb] = (_Float16)a[r];
      }
    }
  }
#undef XSH
#undef LNS
#undef XP
}

// ---------- cooperative fused kernel: all 6 layers, grid.sync between ------
__global__ __launch_bounds__(384, 1) void all_layers_kernel(
    const _Float16* __restrict__ P,
    const float* __restrict__ b_proj,
    const float* __restrict__ ln1_g, const float* __restrict__ ln1_b,
    const float* __restrict__ ln2_g, const float* __restrict__ ln2_b,
    const float* __restrict__ b_ff1, const float* __restrict__ b_ff2,
    const float* __restrict__ lnf_g, const float* __restrict__ lnf_b,
    const float* __restrict__ b_act, float* __restrict__ x,
    _Float16* __restrict__ Q0, _Float16* __restrict__ K0,
    _Float16* __restrict__ V0, _Float16* __restrict__ Q1,
    _Float16* __restrict__ K1, _Float16* __restrict__ V1,
    float* __restrict__ out) {
  __shared__ float smemf[16128];  // 64512 B
#define XSH(g, row, c) ((_Float16*)smemf + (size_t)(g) * 1920 + (row) * 20 + (c))
#define OSH ((_Float16*)smemf + 7680)
#define HSP(g, fp) ((_Float16*)smemf + ((size_t)(g) * 12 + (fp)) * 512)
#define LNS(g, w, r, i) smemf[15360 + (((g) * 6 + (w)) * 16 + (r)) * 2 + (i)]
#define XP(g) (x + ((size_t)(blockIdx.x * 4 + (g)) * 6 + cfo) * 256 + lane * 4)
  cg::grid_group grid = cg::this_grid();
  const int tid = threadIdx.x;
  const int wave = tid >> 6, lane = tid & 63;
  const int lr = lane & 15, lg = lane >> 4;
  const int b = blockIdx.x >> 4, jj = blockIdx.x & 15;
  const int cfo = wave;
  const f4 zero4 = {0.f, 0.f, 0.f, 0.f};
  const h4 ones = {(_Float16)1.f, (_Float16)1.f, (_Float16)1.f, (_Float16)1.f};
  int mrow[4] = {2 * jj, 2 * jj + 1, 62 - 2 * jj, 63 - 2 * jj};
  int tt_[4], tok_[4], t2_[4];
#pragma unroll
  for (int g = 0; g < 4; ++g) {
    tt_[g] = mrow[g] * 16 + lr;
    tok_[g] = b * 1024 + tt_[g];
    t2_[g] = (g < 2) ? jj : 31 - jj;
  }

  for (int l = 0; l < L_; ++l) {
    const bool last = (l == L_ - 1);
    const _Float16* Qs = (l & 1) ? Q1 : Q0;
    const _Float16* Ks = (l & 1) ? K1 : K0;
    const _Float16* Vs = (l & 1) ? V1 : V0;
    _Float16* qp_ = (l & 1) ? Q0 : Q1;
    _Float16* kp_ = (l & 1) ? K0 : K1;
    _Float16* vp_ = (l & 1) ? V0 : V1;
    const _Float16* Wp = P + OFF_PROJ + (size_t)l * 9216;
    const float* bp = b_proj + l * 96;
    const _Float16* W1 = P + OFF_FF1 + (size_t)l * 36864;
    const float* b1 = b_ff1 + l * 384;
    const _Float16* W2 = P + OFF_FF2 + (size_t)l * 36864;
    const float* b2 = b_ff2 + l * 96;
    const float* ln2g = ln2_g + l * 96;
    const float* ln2b = ln2_b + l * 96;
    const float* lntg = last ? lnf_g : ln1_g + (l + 1) * 96;
    const float* lntb = last ? lnf_b : ln1_b + (l + 1) * 96;
    const _Float16* Wtail = last ? (P + OFF_ACT)
                                 : (P + OFF_QKV + (size_t)(l + 1) * 27648);

    // ================= attention phase =================
    {
      const size_t bhoff = (size_t)(b * NH_ + wave) * 16384;
      const _Float16* qB_ = Qs + bhoff;
      const _Float16* kB_ = Ks + bhoff;
      const _Float16* vB_ = Vs + bhoff;
      const int qA = jj, qB2 = 31 - jj;
      h4 qfA0, qfA1, qfB0, qfB1;
      {
        h8 t = *(const h8*)(qB_ + (size_t)qA * 512 + lane * 8);
        qfA0 = __builtin_shufflevector(t, t, 0, 1, 2, 3);
        qfA1 = __builtin_shufflevector(t, t, 4, 5, 6, 7);
        h8 t2v = *(const h8*)(qB_ + (size_t)qB2 * 512 + lane * 8);
        qfB0 = __builtin_shufflevector(t2v, t2v, 0, 1, 2, 3);
        qfB1 = __builtin_shufflevector(t2v, t2v, 4, 5, 6, 7);
      }
      f4 OA0 = zero4, OA1 = zero4, SA0 = zero4, SA1 = zero4;
      f4 OB0 = zero4, OB1 = zero4, SB0 = zero4, SB1 = zero4;
      h4 kc0, kc1, vc0, vc1, kn0, kn1, vn0, vn1;
      ldkv(kB_, vB_, 0, lane, kc0, kc1, vc0, vc1);
      for (int t3 = 0; t3 < qA; ++t3) {
        ldkv(kB_, vB_, t3 + 1, lane, kn0, kn1, vn0, vn1);
        astep_full(kc0, kc1, vc0, vc1, qfA0, qfA1, ones, OA0, OA1, SA0, SA1);
        astep_full(kc0, kc1, vc0, vc1, qfB0, qfB1, ones, OB0, OB1, SB0, SB1);
        kc0 = kn0; kc1 = kn1; vc0 = vn0; vc1 = vn1;
      }
      {
        ldkv(kB_, vB_, qA + 1, lane, kn0, kn1, vn0, vn1);
        astep_diag(kc0, kc1, vc0, vc1, qfA0, qfA1, ones, OA0, OA1, SA0, SA1, lr, lg);
        astep_full(kc0, kc1, vc0, vc1, qfB0, qfB1, ones, OB0, OB1, SB0, SB1);
        kc0 = kn0; kc1 = kn1; vc0 = vn0; vc1 = vn1;
      }
      for (int t3 = qA + 1; t3 < qB2; ++t3) {
        ldkv(kB_, vB_, t3 + 1, lane, kn0, kn1, vn0, vn1);
        astep_full(kc0, kc1, vc0, vc1, qfB0, qfB1, ones, OB0, OB1, SB0, SB1);
        kc0 = kn0; kc1 = kn1; vc0 = vn0; vc1 = vn1;
      }
      astep_diag(kc0, kc1, vc0, vc1, qfB0, qfB1, ones, OB0, OB1, SB0, SB1, lr, lg);
      int stp = wave >> 1;
      int jb = (lr & 3) + (wave & 1) * 4;
      int lgp = lr >> 2;
#pragma unroll
      for (int r = 0; r < 4; ++r) {
        int pos = (lgp * 16 + lg * 4 + r) * 8 + jb;
        OSH[(0 * 3 + stp) * 512 + pos] = (_Float16)(OA0[r] * __builtin_amdgcn_rcpf(SA0[r]));
        OSH[(1 * 3 + stp) * 512 + pos] = (_Float16)(OA1[r] * __builtin_amdgcn_rcpf(SA1[r]));
        OSH[(2 * 3 + stp) * 512 + pos] = (_Float16)(OB0[r] * __builtin_amdgcn_rcpf(SB0[r]));
        OSH[(3 * 3 + stp) * 512 + pos] = (_Float16)(OB1[r] * __builtin_amdgcn_rcpf(SB1[r]));
      }
    }
    __syncthreads();  // A-bar: OSH complete

    // ================= stage =================
    f4 xc[4], x1[4];
    h4 obf[4][6];
#pragma unroll
    for (int g = 0; g < 4; ++g)
#pragma unroll
      for (int stp = 0; stp < 3; ++stp) {
        h8 t = *(const h8*)(OSH + ((size_t)(g * 3 + stp)) * 512 + lane * 8);
        obf[g][2 * stp] = __builtin_shufflevector(t, t, 0, 1, 2, 3);
        obf[g][2 * stp + 1] = __builtin_shufflevector(t, t, 4, 5, 6, 7);
      }
    h4 wf[6];
#pragma unroll
    for (int stp = 0; stp < 3; ++stp)
      ldpair(Wp, cfo * 3 + stp, lane, wf[2 * stp], wf[2 * stp + 1]);
    f4 bb = *(const f4*)(bp + cfo * 16 + lg * 4);
#pragma unroll
    for (int g = 0; g < 4; ++g) {
      f4 a = zero4;
#pragma unroll
      for (int st = 0; st < 6; ++st) a = MFMA16(wf[st], obf[g][st], a, 0, 0, 0);
      f4 xr = *(const f4*)XP(g);
#pragma unroll
      for (int j = 0; j < 4; ++j) x1[g][j] = a[j] + bb[j] + xr[j];
    }
#pragma unroll
    for (int g = 0; g < 4; ++g) {
      float s = x1[g][0] + x1[g][1] + x1[g][2] + x1[g][3];
      float sq = x1[g][0] * x1[g][0] + x1[g][1] * x1[g][1] +
                 x1[g][2] * x1[g][2] + x1[g][3] * x1[g][3];
      s += __shfl_xor(s, 16); sq += __shfl_xor(sq, 16);
      s += __shfl_xor(s, 32); sq += __shfl_xor(sq, 32);
      if (lane < 16) { LNS(g, wave, lr, 0) = s; LNS(g, wave, lr, 1) = sq; }
    }
    __syncthreads();  // B1
    {
      f4 gg4 = *(const f4*)(ln2g + cfo * 16 + lg * 4);
      f4 b4 = *(const f4*)(ln2b + cfo * 16 + lg * 4);
#pragma unroll
      for (int g = 0; g < 4; ++g) {
        float s = 0.f, sq = 0.f;
#pragma unroll
        for (int w = 0; w < 6; ++w) { s += LNS(g, w, lr, 0); sq += LNS(g, w, lr, 1); }
        float mean = s * (1.f / 96.f);
        float rs = rsqrtf(sq * (1.f / 96.f) - mean * mean + 1e-5f);
        h4 xn;
#pragma unroll
        for (int j = 0; j < 4; ++j)
          xn[j] = (_Float16)((x1[g][j] - mean) * rs * gg4[j] + b4[j]);
        *(h4*)XSH(g, cfo * 16 + lr, lg * 4) = xn;
      }
    }
    __syncthreads();  // B2
    h4 xnf[4][6];
#pragma unroll
    for (int g = 0; g < 4; ++g)
#pragma unroll
      for (int st = 0; st < 6; ++st)
        xnf[g][st] = *(const h4*)XSH(g, st * 16 + lr, lg * 4);
    __syncthreads();  // B2b

#pragma unroll
    for (int p = 0; p < 2; ++p) {
      int nf0 = wave * 4 + p * 2;
      h4 wA[6], wB[6];
#pragma unroll
      for (int stp = 0; stp < 3; ++stp) {
        ldpair(W1, nf0 * 3 + stp, lane, wA[2 * stp], wA[2 * stp + 1]);
        ldpair(W1, (nf0 + 1) * 3 + stp, lane, wB[2 * stp], wB[2 * stp + 1]);
      }
      f4 bA = *(const f4*)(b1 + nf0 * 16 + lg * 4);
      f4 bB = *(const f4*)(b1 + (nf0 + 1) * 16 + lg * 4);
#pragma unroll
      for (int g = 0; g < 4; ++g) {
        f4 hA = zero4, hB = zero4;
#pragma unroll
        for (int st = 0; st < 6; ++st) {
          hA = MFMA16(wA[st], xnf[g][st], hA, 0, 0, 0);
          hB = MFMA16(wB[st], xnf[g][st], hB, 0, 0, 0);
        }
        h4 lo, hi;
#pragma unroll
        for (int j = 0; j < 4; ++j) {
          lo[j] = (_Float16)fmaxf(hA[j] + bA[j], 0.f);
          hi[j] = (_Float16)fmaxf(hB[j] + bB[j], 0.f);
        }
        h8 comb = __builtin_shufflevector(lo, hi, 0, 1, 2, 3, 4, 5, 6, 7);
        *(h8*)(HSP(g, wave * 2 + p) + lane * 8) = comb;
      }
    }
    h4 w2f[24];
#pragma unroll
    for (int stp = 0; stp < 12; ++stp)
      ldpair(W2, cfo * 12 + stp, lane, w2f[2 * stp], w2f[2 * stp + 1]);
    __syncthreads();  // B3
    {
      f4 b4 = *(const f4*)(b2 + cfo * 16 + lg * 4);
#pragma unroll
      for (int g = 0; g < 4; ++g) {
        f4 y = zero4;
#pragma unroll
        for (int fp = 0; fp < 12; ++fp) {
          h8 t = *(const h8*)(HSP(g, fp) + lane * 8);
          h4 lo = __builtin_shufflevector(t, t, 0, 1, 2, 3);
          h4 hi = __builtin_shufflevector(t, t, 4, 5, 6, 7);
          y = MFMA16(w2f[2 * fp], lo, y, 0, 0, 0);
          y = MFMA16(w2f[2 * fp + 1], hi, y, 0, 0, 0);
        }
#pragma unroll
        for (int j = 0; j < 4; ++j) xc[g][j] = x1[g][j] + y[j] + b4[j];
        if (!last) *(f4*)XP(g) = xc[g];
      }
    }

#pragma unroll
    for (int g = 0; g < 4; ++g) {
      float s = xc[g][0] + xc[g][1] + xc[g][2] + xc[g][3];
      float sq = xc[g][0] * xc[g][0] + xc[g][1] * xc[g][1] +
                 xc[g][2] * xc[g][2] + xc[g][3] * xc[g][3];
      s += __shfl_xor(s, 16); sq += __shfl_xor(sq, 16);
      s += __shfl_xor(s, 32); sq += __shfl_xor(sq, 32);
      if (lane < 16) { LNS(g, wave, lr, 0) = s; LNS(g, wave, lr, 1) = sq; }
    }
    __syncthreads();  // B4
    {
      f4 gg4 = *(const f4*)(lntg + cfo * 16 + lg * 4);
      f4 b4 = *(const f4*)(lntb + cfo * 16 + lg * 4);
#pragma unroll
      for (int g = 0; g < 4; ++g) {
        float s = 0.f, sq = 0.f;
#pragma unroll
        for (int w = 0; w < 6; ++w) { s += LNS(g, w, lr, 0); sq += LNS(g, w, lr, 1); }
        float mean = s * (1.f / 96.f);
        float rs = rsqrtf(sq * (1.f / 96.f) - mean * mean + 1e-5f);
        h4 xn;
#pragma unroll
        for (int j = 0; j < 4; ++j)
          xn[j] = (_Float16)((xc[g][j] - mean) * rs * gg4[j] + b4[j]);
        *(h4*)XSH(g, cfo * 16 + lr, lg * 4) = xn;
      }
    }
    __syncthreads();  // B5
    if (last) {
      if (wave == 0) {
        h4 wt[6];
#pragma unroll
        for (int stp = 0; stp < 3; ++stp)
          ldpair(Wtail, stp, lane, wt[2 * stp], wt[2 * stp + 1]);
        f4 bbt = *(const f4*)(b_act + lg * 4);
#pragma unroll
        for (int g = 0; g < 4; ++g) {
          f4 a = zero4;
#pragma unroll
          for (int st = 0; st < 6; ++st) {
            h4 xf = *(const h4*)XSH(g, st * 16 + lr, lg * 4);
            a = MFMA16(wt[st], xf, a, 0, 0, 0);
          }
          f4 o;
#pragma unroll
          for (int j = 0; j < 4; ++j) o[j] = a[j] + bbt[j];
          *(f4*)(out + (size_t)tok_[g] * 16 + lg * 4) = o;
        }
      }
    } else {
      h4 xf[4][6];
#pragma unroll
      for (int g = 0; g < 4; ++g)
#pragma unroll
        for (int st = 0; st < 6; ++st)
          xf[g][st] = *(const h4*)XSH(g, st * 16 + lr, lg * 4);
#pragma unroll
      for (int f = 0; f < 3; ++f) {
        int nf = wave * 3 + f;
        h4 wt[6];
#pragma unroll
        for (int stp = 0; stp < 3; ++stp)
          ldpair(Wtail, nf * 3 + stp, lane, wt[2 * stp], wt[2 * stp + 1]);
#pragma unroll
        for (int g = 0; g < 4; ++g) {
          f4 a = zero4;
#pragma unroll
          for (int st = 0; st < 6; ++st) a = MFMA16(wt[st], xf[g][st], a, 0, 0, 0);
          if (nf < 12) {
            int h = nf < 6 ? nf : nf - 6;
            _Float16* dst = (nf < 6 ? qp_ : kp_) +
                            ((size_t)(b * NH_ + h) * 32 + t2_[g]) * 512 +
                            lane * 8 + (g & 1) * 4;
            h4 hv = {(_Float16)a[0], (_Float16)a[1], (_Float16)a[2], (_Float16)a[3]};
            *(h4*)dst = hv;
          } else {
            int hb = nf - 12;
            _Float16* vbase = vp_ + ((size_t)(b * NH_ + hb) * 32 + t2_[g]) * 512;
            int jb = (lr & 3) + (g & 1) * 4;
            int lgp = lr >> 2;
#pragma unroll
            for (int r = 0; r < 4; ++r)
              vbase[(lgp * 16 + lg * 4 + r) * 8 + jb] = (_Float16)a[r];
          }
        }
      }
    }
    if (!last) {
      __threadfence();
      grid.sync();
      __syncthreads();
    }
  }
#undef XSH
#undef OSH
#undef HSP
#undef LNS
#undef XP
}

extern "C" void kernel_launch(void* const* d_in, const int* in_sizes, int n_in,
                              void* d_out, int out_size, void* d_ws, size_t ws_size,
                              hipStream_t stream) {
  const float* goals   = (const float*)d_in[0];
  const float* obss    = (const float*)d_in[1];
  const float* w_go    = (const float*)d_in[2];
  const float* b_go    = (const float*)d_in[3];
  const float* pos_emb = (const float*)d_in[4];
  const float* wq      = (const float*)d_in[5];
  const float* wk      = (const float*)d_in[6];
  const float* wv      = (const float*)d_in[7];
  const float* w_proj  = (const float*)d_in[8];
  const float* b_proj  = (const float*)d_in[9];
  const float* ln1_g   = (const float*)d_in[10];
  const float* ln1_b   = (const float*)d_in[11];
  const float* ln2_g   = (const float*)d_in[12];
  const float* ln2_b   = (const float*)d_in[13];
  const float* w_ff1   = (const float*)d_in[14];
  const float* b_ff1   = (const float*)d_in[15];
  const float* w_ff2   = (const float*)d_in[16];
  const float* b_ff2   = (const float*)d_in[17];
  const float* lnf_g   = (const float*)d_in[18];
  const float* lnf_b   = (const float*)d_in[19];
  const float* w_act   = (const float*)d_in[20];
  const float* b_act   = (const float*)d_in[21];
  float* out = (float*)d_out;

  const int M = B_ * T_;  // 16384
  float* ws = (float*)d_ws;
  size_t off = 0;
  _Float16* P = (_Float16*)(ws + off); off += PACK_TOTAL / 2 + 64;
  float* x = ws + off; off += (size_t)M * 96;
  _Float16* Qb[2]; _Float16* Kb[2]; _Float16* Vb[2];
  for (int p = 0; p < 2; ++p) {
    Qb[p] = (_Float16*)(ws + off); off += (size_t)M * 48;
    Kb[p] = (_Float16*)(ws + off); off += (size_t)M * 48;
    Vb[p] = (_Float16*)(ws + off); off += (size_t)M * 48;
  }

  pack_all_kernel<<<(PACK_TOTAL + 255) / 256, 256, 0, stream>>>(
      w_go, wq, wk, wv, w_proj, w_ff1, w_ff2, w_act, P);

  embed_kernel<<<256, 384, 0, stream>>>(
      goals, obss, pos_emb, b_go, P + OFF_GO, x, ln1_g, ln1_b,
      P + OFF_QKV, Qb[0], Kb[0], Vb[0]);

  {
    void* args[] = {
      (void*)&P, (void*)&b_proj, (void*)&ln1_g, (void*)&ln1_b,
      (void*)&ln2_g, (void*)&ln2_b, (void*)&b_ff1, (void*)&b_ff2,
      (void*)&lnf_g, (void*)&lnf_b, (void*)&b_act, (void*)&x,
      (void*)&Qb[0], (void*)&Kb[0], (void*)&Vb[0],
      (void*)&Qb[1], (void*)&Kb[1], (void*)&Vb[1], (void*)&out,
    };
    hipLaunchCooperativeKernel((const void*)all_layers_kernel, dim3(256),
                               dim3(384), args, 0, stream);
  }
}

// Round 23
// 186.470 us; speedup vs baseline: 3.1841x; 3.1841x over previous
//
#include <hip/hip_runtime.h>
#include <math.h>

#define B_ 16
#define T_ 1024
#define D_ 96
#define L_ 6
#define NH_ 6
#define HS_ 16
#define FF_ 384

typedef _Float16 h4 __attribute__((ext_vector_type(4)));
typedef _Float16 h8 __attribute__((ext_vector_type(8)));
typedef __fp16 g2 __attribute__((ext_vector_type(2)));
typedef __fp16 g4 __attribute__((ext_vector_type(4)));
typedef float f4 __attribute__((ext_vector_type(4)));

#define MFMA16 __builtin_amdgcn_mfma_f32_16x16x16f16

// packed f16 weights, layout [frag][stp][lane 0..63][8 halves]
#define OFF_GO   0
#define OFF_QKV  9216
#define OFF_PROJ 175104
#define OFF_FF1  230400
#define OFF_FF2  451584
#define OFF_ACT  672768
#define PACK_TOTAL 674304

// Q weights pre-scaled by 1/sqrt(16) * log2(e) so attn uses exp2 directly.
#define QSCALE 0.3606737602222409f

static __device__ __forceinline__ h4 pk4(const float* p) {
  g2 lo = __builtin_amdgcn_cvt_pkrtz(p[0], p[1]);
  g2 hi = __builtin_amdgcn_cvt_pkrtz(p[2], p[3]);
  g4 r4 = __builtin_shufflevector(lo, hi, 0, 1, 2, 3);
  return __builtin_bit_cast(h4, r4);
}

static __device__ __forceinline__ void ldpair(const _Float16* base, int blk,
                                              int lane, h4& a, h4& b) {
  h8 t = *(const h8*)(base + (size_t)blk * 512 + lane * 8);
  a = __builtin_shufflevector(t, t, 0, 1, 2, 3);
  b = __builtin_shufflevector(t, t, 4, 5, 6, 7);
}

static __device__ __forceinline__ void ldkv(const _Float16* kB_, const _Float16* vB_,
                                            int tile, int lane,
                                            h4& k0, h4& k1, h4& v0, h4& v1) {
  h8 kt = *(const h8*)(kB_ + (size_t)tile * 512 + lane * 8);
  k0 = __builtin_shufflevector(kt, kt, 0, 1, 2, 3);
  k1 = __builtin_shufflevector(kt, kt, 4, 5, 6, 7);
  h8 vt = *(const h8*)(vB_ + (size_t)tile * 512 + lane * 8);
  v0 = __builtin_shufflevector(vt, vt, 0, 1, 2, 3);
  v1 = __builtin_shufflevector(vt, vt, 4, 5, 6, 7);
}

// full tile step: 2 q-subtiles vs one K/V tile
static __device__ __forceinline__ void astep_full(
    const h4& kc0, const h4& kc1, const h4& vc0, const h4& vc1,
    const h4& qf0, const h4& qf1, const h4& ones,
    f4& O0, f4& O1, f4& S0, f4& S1) {
  const f4 zero4 = {0.f, 0.f, 0.f, 0.f};
  f4 sa0 = MFMA16(kc0, qf0, zero4, 0, 0, 0);
  f4 sa1 = MFMA16(kc1, qf0, zero4, 0, 0, 0);
  f4 sb0 = MFMA16(kc0, qf1, zero4, 0, 0, 0);
  f4 sb1 = MFMA16(kc1, qf1, zero4, 0, 0, 0);
  float pa0[4], pa1[4], pb0[4], pb1[4];
#pragma unroll
  for (int r = 0; r < 4; ++r) {
    pa0[r] = __builtin_amdgcn_exp2f(sa0[r]);
    pa1[r] = __builtin_amdgcn_exp2f(sa1[r]);
    pb0[r] = __builtin_amdgcn_exp2f(sb0[r]);
    pb1[r] = __builtin_amdgcn_exp2f(sb1[r]);
  }
  h4 fa0 = pk4(pa0), fa1 = pk4(pa1), fb0 = pk4(pb0), fb1 = pk4(pb1);
  O0 = MFMA16(fa0, vc0, O0, 0, 0, 0);
  O0 = MFMA16(fa1, vc1, O0, 0, 0, 0);
  S0 = MFMA16(fa0, ones, S0, 0, 0, 0);
  S0 = MFMA16(fa1, ones, S0, 0, 0, 0);
  O1 = MFMA16(fb0, vc0, O1, 0, 0, 0);
  O1 = MFMA16(fb1, vc1, O1, 0, 0, 0);
  S1 = MFMA16(fb0, ones, S1, 0, 0, 0);
  S1 = MFMA16(fb1, ones, S1, 0, 0, 0);
}

// diagonal tile step (causal): u0 sees half0 masked; u1 half0 full + half1 masked
static __device__ __forceinline__ void astep_diag(
    const h4& kc0, const h4& kc1, const h4& vc0, const h4& vc1,
    const h4& qf0, const h4& qf1, const h4& ones,
    f4& O0, f4& O1, f4& S0, f4& S1, int lr, int lg) {
  const f4 zero4 = {0.f, 0.f, 0.f, 0.f};
  f4 sa0 = MFMA16(kc0, qf0, zero4, 0, 0, 0);
  float pa0[4];
#pragma unroll
  for (int r = 0; r < 4; ++r)
    pa0[r] = (lg * 4 + r <= lr) ? __builtin_amdgcn_exp2f(sa0[r]) : 0.f;
  h4 fa0 = pk4(pa0);
  O0 = MFMA16(fa0, vc0, O0, 0, 0, 0);
  S0 = MFMA16(fa0, ones, S0, 0, 0, 0);
  f4 sb0 = MFMA16(kc0, qf1, zero4, 0, 0, 0);
  f4 sb1 = MFMA16(kc1, qf1, zero4, 0, 0, 0);
  float pb0[4], pb1[4];
#pragma unroll
  for (int r = 0; r < 4; ++r) {
    pb0[r] = __builtin_amdgcn_exp2f(sb0[r]);
    pb1[r] = (lg * 4 + r <= lr) ? __builtin_amdgcn_exp2f(sb1[r]) : 0.f;
  }
  h4 fb0 = pk4(pb0), fb1 = pk4(pb1);
  O1 = MFMA16(fb0, vc0, O1, 0, 0, 0);
  O1 = MFMA16(fb1, vc1, O1, 0, 0, 0);
  S1 = MFMA16(fb0, ones, S1, 0, 0, 0);
  S1 = MFMA16(fb1, ones, S1, 0, 0, 0);
}

// ---------- pack all weights into paired-fragment layout ----------
__global__ __launch_bounds__(256) void pack_all_kernel(
    const float* __restrict__ w_go, const float* __restrict__ wq,
    const float* __restrict__ wk, const float* __restrict__ wv,
    const float* __restrict__ w_proj, const float* __restrict__ w_ff1,
    const float* __restrict__ w_ff2, const float* __restrict__ w_act,
    _Float16* __restrict__ P) {
  int i = blockIdx.x * 256 + threadIdx.x;
  if (i >= PACK_TOTAL) return;
  float v;
  if (i < OFF_QKV) {                       // GO: 6 frags, 3 stp
    int o = i, nf = o / 1536, r = o % 1536, stp = r / 512, q = r & 511;
    int lane = q >> 3, h8i = q & 7, lr = lane & 15, lg = lane >> 4;
    int st = stp * 2 + (h8i >> 2), j = h8i & 3;
    int n = nf * 16 + lr, k = st * 16 + lg * 4 + j;
    v = w_go[k * 96 + n];
  } else if (i < OFF_PROJ) {               // QKV: per layer 18 frags, 3 stp
    int o = i - OFF_QKV, l = o / 27648, r0 = o % 27648;
    int nf = r0 / 1536, r = r0 % 1536, stp = r / 512, q = r & 511;
    int lane = q >> 3, h8i = q & 7, lr = lane & 15, lg = lane >> 4;
    int st = stp * 2 + (h8i >> 2), j = h8i & 3;
    int c = nf * 16 + lr, k = st * 16 + lg * 4 + j;
    int which = c / 96, hc = c % 96, h = hc >> 4, jx = hc & 15;
    const float* s = (which == 0) ? wq : (which == 1 ? wk : wv);
    v = s[((l * NH_ + h) * 96 + k) * 16 + jx];
    if (which == 0) v *= QSCALE;
  } else if (i < OFF_FF1) {                // PROJ: per layer 6 frags, 3 stp
    int o = i - OFF_PROJ, l = o / 9216, r0 = o % 9216;
    int nf = r0 / 1536, r = r0 % 1536, stp = r / 512, q = r & 511;
    int lane = q >> 3, h8i = q & 7, lr = lane & 15, lg = lane >> 4;
    int st = stp * 2 + (h8i >> 2), j = h8i & 3;
    int n = nf * 16 + lr, k = st * 16 + lg * 4 + j;
    v = w_proj[l * 9216 + k * 96 + n];
  } else if (i < OFF_FF2) {                // FF1: per layer 24 frags, 3 stp
    int o = i - OFF_FF1, l = o / 36864, r0 = o % 36864;
    int nf = r0 / 1536, r = r0 % 1536, stp = r / 512, q = r & 511;
    int lane = q >> 3, h8i = q & 7, lr = lane & 15, lg = lane >> 4;
    int st = stp * 2 + (h8i >> 2), j = h8i & 3;
    int n = nf * 16 + lr, k = st * 16 + lg * 4 + j;
    v = w_ff1[l * 36864 + k * 384 + n];
  } else if (i < OFF_ACT) {                // FF2: per layer 6 frags, 12 stp
    int o = i - OFF_FF2, l = o / 36864, r0 = o % 36864;
    int nf = r0 / 6144, r = r0 % 6144, stp = r / 512, q = r & 511;
    int lane = q >> 3, h8i = q & 7, lr = lane & 15, lg = lane >> 4;
    int st = stp * 2 + (h8i >> 2), j = h8i & 3;
    int n = nf * 16 + lr, k = st * 16 + lg * 4 + j;
    v = w_ff2[l * 36864 + k * 96 + n];
  } else {                                 // ACT: 1 frag, 3 stp
    int o = i - OFF_ACT, stp = o / 512, q = o & 511;
    int lane = q >> 3, h8i = q & 7, lr = lane & 15, lg = lane >> 4;
    int st = stp * 2 + (h8i >> 2), j = h8i & 3;
    int k = st * 16 + lg * 4 + j;
    v = w_act[k * 16 + lr];
  }
  P[i] = (_Float16)v;
}

// Shared mapping: block (b=blk>>4, jj=blk&15) owns batch-b chunks
// m = {2jj, 2jj+1, 62-2jj, 63-2jj} (mirrored for causal attn balance).
// x residual slots: [(blk*4+g)*6+cf][lane][4] fp32 (slot-addressed).
// QKV paired tiles: [bh][tile32][lane][8]; chunk g -> tile (g<2?jj:31-jj), half g&1.

// ---------- embed kernel: concat+embed+pos -> x; LN1+qkv -> QKV[0] ----------
__global__ __launch_bounds__(384, 1) void embed_kernel(
    const float* __restrict__ goals, const float* __restrict__ obss,
    const float* __restrict__ pos, const float* __restrict__ b_go,
    const _Float16* __restrict__ Wp, float* __restrict__ x,
    const float* __restrict__ lntg, const float* __restrict__ lntb,
    const _Float16* __restrict__ Wtail,
    _Float16* __restrict__ qp_, _Float16* __restrict__ kp_,
    _Float16* __restrict__ vp_) {
  __shared__ float smemf[16128];
#define XSH(g, row, c) ((_Float16*)smemf + (size_t)(g) * 1920 + (row) * 20 + (c))
#define LNS(g, w, r, i) smemf[15360 + (((g) * 6 + (w)) * 16 + (r)) * 2 + (i)]
#define XP(g) (x + ((size_t)(blockIdx.x * 4 + (g)) * 6 + cfo) * 256 + lane * 4)
  const int tid = threadIdx.x;
  const int wave = tid >> 6, lane = tid & 63;
  const int lr = lane & 15, lg = lane >> 4;
  const int b = blockIdx.x >> 4, jj = blockIdx.x & 15;
  const int cfo = wave;
  const f4 zero4 = {0.f, 0.f, 0.f, 0.f};
  int mrow[4] = {2 * jj, 2 * jj + 1, 62 - 2 * jj, 63 - 2 * jj};
  int tt_[4], t2_[4];
#pragma unroll
  for (int g = 0; g < 4; ++g) { tt_[g] = mrow[g] * 16 + lr; t2_[g] = (g < 2) ? jj : 31 - jj; }

  f4 xc[4];
  h4 ef[4][6];
#pragma unroll
  for (int st = 0; st < 2; ++st) {
    f4 s4 = *(const f4*)(goals + b * 32 + st * 16 + lg * 4);
    h4 e = (h4){(_Float16)s4[0], (_Float16)s4[1], (_Float16)s4[2], (_Float16)s4[3]};
#pragma unroll
    for (int g = 0; g < 4; ++g) ef[g][st] = e;
  }
#pragma unroll
  for (int g = 0; g < 4; ++g)
#pragma unroll
    for (int st = 2; st < 6; ++st) {
      f4 s4 = *(const f4*)(obss + (size_t)(b * 1024 + tt_[g]) * 64 +
                           (st - 2) * 16 + lg * 4);
      ef[g][st] = (h4){(_Float16)s4[0], (_Float16)s4[1], (_Float16)s4[2], (_Float16)s4[3]};
    }
  h4 wf[6];
#pragma unroll
  for (int stp = 0; stp < 3; ++stp)
    ldpair(Wp, cfo * 3 + stp, lane, wf[2 * stp], wf[2 * stp + 1]);
  f4 bb = *(const f4*)(b_go + cfo * 16 + lg * 4);
#pragma unroll
  for (int g = 0; g < 4; ++g) {
    f4 a = zero4;
#pragma unroll
    for (int st = 0; st < 6; ++st) a = MFMA16(wf[st], ef[g][st], a, 0, 0, 0);
    f4 pp = *(const f4*)(pos + (size_t)tt_[g] * 96 + cfo * 16 + lg * 4);
#pragma unroll
    for (int j = 0; j < 4; ++j) xc[g][j] = a[j] + bb[j] + pp[j];
    *(f4*)XP(g) = xc[g];
  }

  // LN1 + qkv tail
#pragma unroll
  for (int g = 0; g < 4; ++g) {
    float s = xc[g][0] + xc[g][1] + xc[g][2] + xc[g][3];
    float sq = xc[g][0] * xc[g][0] + xc[g][1] * xc[g][1] +
               xc[g][2] * xc[g][2] + xc[g][3] * xc[g][3];
    s += __shfl_xor(s, 16); sq += __shfl_xor(sq, 16);
    s += __shfl_xor(s, 32); sq += __shfl_xor(sq, 32);
    if (lane < 16) { LNS(g, wave, lr, 0) = s; LNS(g, wave, lr, 1) = sq; }
  }
  __syncthreads();
  {
    f4 gg4 = *(const f4*)(lntg + cfo * 16 + lg * 4);
    f4 b4 = *(const f4*)(lntb + cfo * 16 + lg * 4);
#pragma unroll
    for (int g = 0; g < 4; ++g) {
      float s = 0.f, sq = 0.f;
#pragma unroll
      for (int w = 0; w < 6; ++w) { s += LNS(g, w, lr, 0); sq += LNS(g, w, lr, 1); }
      float mean = s * (1.f / 96.f);
      float rs = rsqrtf(sq * (1.f / 96.f) - mean * mean + 1e-5f);
      h4 xn;
#pragma unroll
      for (int j = 0; j < 4; ++j)
        xn[j] = (_Float16)((xc[g][j] - mean) * rs * gg4[j] + b4[j]);
      *(h4*)XSH(g, cfo * 16 + lr, lg * 4) = xn;
    }
  }
  __syncthreads();
  h4 xf[4][6];
#pragma unroll
  for (int g = 0; g < 4; ++g)
#pragma unroll
    for (int st = 0; st < 6; ++st)
      xf[g][st] = *(const h4*)XSH(g, st * 16 + lr, lg * 4);
#pragma unroll
  for (int f = 0; f < 3; ++f) {
    int nf = wave * 3 + f;
    h4 wt[6];
#pragma unroll
    for (int stp = 0; stp < 3; ++stp)
      ldpair(Wtail, nf * 3 + stp, lane, wt[2 * stp], wt[2 * stp + 1]);
#pragma unroll
    for (int g = 0; g < 4; ++g) {
      f4 a = zero4;
#pragma unroll
      for (int st = 0; st < 6; ++st) a = MFMA16(wt[st], xf[g][st], a, 0, 0, 0);
      if (nf < 12) {
        int h = nf < 6 ? nf : nf - 6;
        _Float16* dst = (nf < 6 ? qp_ : kp_) +
                        ((size_t)(b * NH_ + h) * 32 + t2_[g]) * 512 +
                        lane * 8 + (g & 1) * 4;
        h4 hv = {(_Float16)a[0], (_Float16)a[1], (_Float16)a[2], (_Float16)a[3]};
        *(h4*)dst = hv;
      } else {
        int hb = nf - 12;
        _Float16* vbase = vp_ + ((size_t)(b * NH_ + hb) * 32 + t2_[g]) * 512;
        int jb = (lr & 3) + (g & 1) * 4;
        int lgp = lr >> 2;
#pragma unroll
        for (int r = 0; r < 4; ++r)
          vbase[(lgp * 16 + lg * 4 + r) * 8 + jb] = (_Float16)a[r];
      }
    }
  }
#undef XSH
#undef LNS
#undef XP
}

// ---------- fused layer kernel: attn (LDS out) + proj + MLP + (qkv|head) ----
// attn: wave = head; dual q-blocks qA=jj (chunks 0,1), qB=31-jj (chunks 2,3)
// share one K/V tile stream (1 tile load -> 4 q-subtiles).
template <bool HEAD>
__global__ __launch_bounds__(384, 1) void layer_kernel(
    const _Float16* __restrict__ Qs, const _Float16* __restrict__ Ks,
    const _Float16* __restrict__ Vs,
    const _Float16* __restrict__ Wp, const float* __restrict__ bp,
    float* __restrict__ x,
    const _Float16* __restrict__ W1, const float* __restrict__ b1,
    const _Float16* __restrict__ W2, const float* __restrict__ b2,
    const float* __restrict__ ln2g, const float* __restrict__ ln2b,
    const float* __restrict__ lntg, const float* __restrict__ lntb,
    const _Float16* __restrict__ Wtail, const float* __restrict__ btail,
    _Float16* __restrict__ qp_, _Float16* __restrict__ kp_,
    _Float16* __restrict__ vp_, float* __restrict__ out) {
  __shared__ float smemf[16128];  // 64512 B
#define XSH(g, row, c) ((_Float16*)smemf + (size_t)(g) * 1920 + (row) * 20 + (c))
#define OSH ((_Float16*)smemf + 7680)
#define HSP(g, fp) ((_Float16*)smemf + ((size_t)(g) * 12 + (fp)) * 512)
#define LNS(g, w, r, i) smemf[15360 + (((g) * 6 + (w)) * 16 + (r)) * 2 + (i)]
#define XP(g) (x + ((size_t)(blockIdx.x * 4 + (g)) * 6 + cfo) * 256 + lane * 4)
  const int tid = threadIdx.x;
  const int wave = tid >> 6, lane = tid & 63;
  const int lr = lane & 15, lg = lane >> 4;
  const int b = blockIdx.x >> 4, jj = blockIdx.x & 15;
  const int cfo = wave;
  const f4 zero4 = {0.f, 0.f, 0.f, 0.f};
  const h4 ones = {(_Float16)1.f, (_Float16)1.f, (_Float16)1.f, (_Float16)1.f};
  int mrow[4] = {2 * jj, 2 * jj + 1, 62 - 2 * jj, 63 - 2 * jj};
  int tt_[4], tok_[4], t2_[4];
#pragma unroll
  for (int g = 0; g < 4; ++g) {
    tt_[g] = mrow[g] * 16 + lr;
    tok_[g] = b * 1024 + tt_[g];
    t2_[g] = (g < 2) ? jj : 31 - jj;
  }

  // ================= attention phase =================
  {
    const size_t bhoff = (size_t)(b * NH_ + wave) * 16384;
    const _Float16* qB_ = Qs + bhoff;
    const _Float16* kB_ = Ks + bhoff;
    const _Float16* vB_ = Vs + bhoff;
    const int qA = jj, qB2 = 31 - jj;  // qA < qB2 always (jj in 0..15)
    h4 qfA0, qfA1, qfB0, qfB1;
    {
      h8 t = *(const h8*)(qB_ + (size_t)qA * 512 + lane * 8);
      qfA0 = __builtin_shufflevector(t, t, 0, 1, 2, 3);
      qfA1 = __builtin_shufflevector(t, t, 4, 5, 6, 7);
      h8 t2v = *(const h8*)(qB_ + (size_t)qB2 * 512 + lane * 8);
      qfB0 = __builtin_shufflevector(t2v, t2v, 0, 1, 2, 3);
      qfB1 = __builtin_shufflevector(t2v, t2v, 4, 5, 6, 7);
    }
    f4 OA0 = zero4, OA1 = zero4, SA0 = zero4, SA1 = zero4;
    f4 OB0 = zero4, OB1 = zero4, SB0 = zero4, SB1 = zero4;
    h4 kc0, kc1, vc0, vc1, kn0, kn1, vn0, vn1;
    ldkv(kB_, vB_, 0, lane, kc0, kc1, vc0, vc1);
    for (int t3 = 0; t3 < qA; ++t3) {
      ldkv(kB_, vB_, t3 + 1, lane, kn0, kn1, vn0, vn1);
      astep_full(kc0, kc1, vc0, vc1, qfA0, qfA1, ones, OA0, OA1, SA0, SA1);
      astep_full(kc0, kc1, vc0, vc1, qfB0, qfB1, ones, OB0, OB1, SB0, SB1);
      kc0 = kn0; kc1 = kn1; vc0 = vn0; vc1 = vn1;
    }
    // tile qA: A diag + B full; prefetch qA+1 (always <= qB2 <= 31)
    {
      ldkv(kB_, vB_, qA + 1, lane, kn0, kn1, vn0, vn1);
      astep_diag(kc0, kc1, vc0, vc1, qfA0, qfA1, ones, OA0, OA1, SA0, SA1, lr, lg);
      astep_full(kc0, kc1, vc0, vc1, qfB0, qfB1, ones, OB0, OB1, SB0, SB1);
      kc0 = kn0; kc1 = kn1; vc0 = vn0; vc1 = vn1;
    }
    for (int t3 = qA + 1; t3 < qB2; ++t3) {
      ldkv(kB_, vB_, t3 + 1, lane, kn0, kn1, vn0, vn1);
      astep_full(kc0, kc1, vc0, vc1, qfB0, qfB1, ones, OB0, OB1, SB0, SB1);
      kc0 = kn0; kc1 = kn1; vc0 = vn0; vc1 = vn1;
    }
    astep_diag(kc0, kc1, vc0, vc1, qfB0, qfB1, ones, OB0, OB1, SB0, SB1, lr, lg);
    // write OSH (chunk g, stp = head>>1, half = head&1)
    int stp = wave >> 1;
    int jb = (lr & 3) + (wave & 1) * 4;
    int lgp = lr >> 2;
#pragma unroll
    for (int r = 0; r < 4; ++r) {
      int pos = (lgp * 16 + lg * 4 + r) * 8 + jb;
      OSH[(0 * 3 + stp) * 512 + pos] = (_Float16)(OA0[r] * __builtin_amdgcn_rcpf(SA0[r]));
      OSH[(1 * 3 + stp) * 512 + pos] = (_Float16)(OA1[r] * __builtin_amdgcn_rcpf(SA1[r]));
      OSH[(2 * 3 + stp) * 512 + pos] = (_Float16)(OB0[r] * __builtin_amdgcn_rcpf(SB0[r]));
      OSH[(3 * 3 + stp) * 512 + pos] = (_Float16)(OB1[r] * __builtin_amdgcn_rcpf(SB1[r]));
    }
  }
  __syncthreads();  // A-bar: OSH complete

  // ================= stage =================
  f4 xc[4], x1[4];
  // ---- proj + resid: obf from OSH ----
  h4 obf[4][6];
#pragma unroll
  for (int g = 0; g < 4; ++g)
#pragma unroll
    for (int stp = 0; stp < 3; ++stp) {
      h8 t = *(const h8*)(OSH + ((size_t)(g * 3 + stp)) * 512 + lane * 8);
      obf[g][2 * stp] = __builtin_shufflevector(t, t, 0, 1, 2, 3);
      obf[g][2 * stp + 1] = __builtin_shufflevector(t, t, 4, 5, 6, 7);
    }
  h4 wf[6];
#pragma unroll
  for (int stp = 0; stp < 3; ++stp)
    ldpair(Wp, cfo * 3 + stp, lane, wf[2 * stp], wf[2 * stp + 1]);
  f4 bb = *(const f4*)(bp + cfo * 16 + lg * 4);
#pragma unroll
  for (int g = 0; g < 4; ++g) {
    f4 a = zero4;
#pragma unroll
    for (int st = 0; st < 6; ++st) a = MFMA16(wf[st], obf[g][st], a, 0, 0, 0);
    f4 xr = *(const f4*)XP(g);
#pragma unroll
    for (int j = 0; j < 4; ++j) x1[g][j] = a[j] + bb[j] + xr[j];
  }
  // ---- LN2 ----
#pragma unroll
  for (int g = 0; g < 4; ++g) {
    float s = x1[g][0] + x1[g][1] + x1[g][2] + x1[g][3];
    float sq = x1[g][0] * x1[g][0] + x1[g][1] * x1[g][1] +
               x1[g][2] * x1[g][2] + x1[g][3] * x1[g][3];
    s += __shfl_xor(s, 16); sq += __shfl_xor(sq, 16);
    s += __shfl_xor(s, 32); sq += __shfl_xor(sq, 32);
    if (lane < 16) { LNS(g, wave, lr, 0) = s; LNS(g, wave, lr, 1) = sq; }
  }
  __syncthreads();  // B1
  {
    f4 gg4 = *(const f4*)(ln2g + cfo * 16 + lg * 4);
    f4 b4 = *(const f4*)(ln2b + cfo * 16 + lg * 4);
#pragma unroll
    for (int g = 0; g < 4; ++g) {
      float s = 0.f, sq = 0.f;
#pragma unroll
      for (int w = 0; w < 6; ++w) { s += LNS(g, w, lr, 0); sq += LNS(g, w, lr, 1); }
      float mean = s * (1.f / 96.f);
      float rs = rsqrtf(sq * (1.f / 96.f) - mean * mean + 1e-5f);
      h4 xn;
#pragma unroll
      for (int j = 0; j < 4; ++j)
        xn[j] = (_Float16)((x1[g][j] - mean) * rs * gg4[j] + b4[j]);
      *(h4*)XSH(g, cfo * 16 + lr, lg * 4) = xn;
    }
  }
  __syncthreads();  // B2
  h4 xnf[4][6];
#pragma unroll
  for (int g = 0; g < 4; ++g)
#pragma unroll
    for (int st = 0; st < 6; ++st)
      xnf[g][st] = *(const h4*)XSH(g, st * 16 + lr, lg * 4);
  __syncthreads();  // B2b: XSH/OSH dead, HSP may overlay

  // ---- ff1 + relu -> HSP pairs ----
#pragma unroll
  for (int p = 0; p < 2; ++p) {
    int nf0 = wave * 4 + p * 2;
    h4 wA[6], wB[6];
#pragma unroll
    for (int stp = 0; stp < 3; ++stp) {
      ldpair(W1, nf0 * 3 + stp, lane, wA[2 * stp], wA[2 * stp + 1]);
      ldpair(W1, (nf0 + 1) * 3 + stp, lane, wB[2 * stp], wB[2 * stp + 1]);
    }
    f4 bA = *(const f4*)(b1 + nf0 * 16 + lg * 4);
    f4 bB = *(const f4*)(b1 + (nf0 + 1) * 16 + lg * 4);
#pragma unroll
    for (int g = 0; g < 4; ++g) {
      f4 hA = zero4, hB = zero4;
#pragma unroll
      for (int st = 0; st < 6; ++st) {
        hA = MFMA16(wA[st], xnf[g][st], hA, 0, 0, 0);
        hB = MFMA16(wB[st], xnf[g][st], hB, 0, 0, 0);
      }
      h4 lo, hi;
#pragma unroll
      for (int j = 0; j < 4; ++j) {
        lo[j] = (_Float16)fmaxf(hA[j] + bA[j], 0.f);
        hi[j] = (_Float16)fmaxf(hB[j] + bB[j], 0.f);
      }
      h8 comb = __builtin_shufflevector(lo, hi, 0, 1, 2, 3, 4, 5, 6, 7);
      *(h8*)(HSP(g, wave * 2 + p) + lane * 8) = comb;
    }
  }
  // ---- ff2 ----
  h4 w2f[24];
#pragma unroll
  for (int stp = 0; stp < 12; ++stp)
    ldpair(W2, cfo * 12 + stp, lane, w2f[2 * stp], w2f[2 * stp + 1]);
  __syncthreads();  // B3
  {
    f4 b4 = *(const f4*)(b2 + cfo * 16 + lg * 4);
#pragma unroll
    for (int g = 0; g < 4; ++g) {
      f4 y = zero4;
#pragma unroll
      for (int fp = 0; fp < 12; ++fp) {
        h8 t = *(const h8*)(HSP(g, fp) + lane * 8);
        h4 lo = __builtin_shufflevector(t, t, 0, 1, 2, 3);
        h4 hi = __builtin_shufflevector(t, t, 4, 5, 6, 7);
        y = MFMA16(w2f[2 * fp], lo, y, 0, 0, 0);
        y = MFMA16(w2f[2 * fp + 1], hi, y, 0, 0, 0);
      }
#pragma unroll
      for (int j = 0; j < 4; ++j) xc[g][j] = x1[g][j] + y[j] + b4[j];
      if constexpr (!HEAD)
        *(f4*)XP(g) = xc[g];
    }
  }

  // ---- tail LN on xc ----
#pragma unroll
  for (int g = 0; g < 4; ++g) {
    float s = xc[g][0] + xc[g][1] + xc[g][2] + xc[g][3];
    float sq = xc[g][0] * xc[g][0] + xc[g][1] * xc[g][1] +
               xc[g][2] * xc[g][2] + xc[g][3] * xc[g][3];
    s += __shfl_xor(s, 16); sq += __shfl_xor(sq, 16);
    s += __shfl_xor(s, 32); sq += __shfl_xor(sq, 32);
    if (lane < 16) { LNS(g, wave, lr, 0) = s; LNS(g, wave, lr, 1) = sq; }
  }
  __syncthreads();  // B4
  {
    f4 gg4 = *(const f4*)(lntg + cfo * 16 + lg * 4);
    f4 b4 = *(const f4*)(lntb + cfo * 16 + lg * 4);
#pragma unroll
    for (int g = 0; g < 4; ++g) {
      float s = 0.f, sq = 0.f;
#pragma unroll
      for (int w = 0; w < 6; ++w) { s += LNS(g, w, lr, 0); sq += LNS(g, w, lr, 1); }
      float mean = s * (1.f / 96.f);
      float rs = rsqrtf(sq * (1.f / 96.f) - mean * mean + 1e-5f);
      h4 xn;
#pragma unroll
      for (int j = 0; j < 4; ++j)
        xn[j] = (_Float16)((xc[g][j] - mean) * rs * gg4[j] + b4[j]);
      *(h4*)XSH(g, cfo * 16 + lr, lg * 4) = xn;
    }
  }
  __syncthreads();  // B5
  if constexpr (HEAD) {
    if (wave == 0) {
      h4 wt[6];
#pragma unroll
      for (int stp = 0; stp < 3; ++stp)
        ldpair(Wtail, stp, lane, wt[2 * stp], wt[2 * stp + 1]);
      f4 bbt = *(const f4*)(btail + lg * 4);
#pragma unroll
      for (int g = 0; g < 4; ++g) {
        f4 a = zero4;
#pragma unroll
        for (int st = 0; st < 6; ++st) {
          h4 xf = *(const h4*)XSH(g, st * 16 + lr, lg * 4);
          a = MFMA16(wt[st], xf, a, 0, 0, 0);
        }
        f4 o;
#pragma unroll
        for (int j = 0; j < 4; ++j) o[j] = a[j] + bbt[j];
        *(f4*)(out + (size_t)tok_[g] * 16 + lg * 4) = o;
      }
    }
  } else {
    h4 xf[4][6];
#pragma unroll
    for (int g = 0; g < 4; ++g)
#pragma unroll
      for (int st = 0; st < 6; ++st)
        xf[g][st] = *(const h4*)XSH(g, st * 16 + lr, lg * 4);
#pragma unroll
    for (int f = 0; f < 3; ++f) {
      int nf = wave * 3 + f;
      h4 wt[6];
#pragma unroll
      for (int stp = 0; stp < 3; ++stp)
        ldpair(Wtail, nf * 3 + stp, lane, wt[2 * stp], wt[2 * stp + 1]);
#pragma unroll
      for (int g = 0; g < 4; ++g) {
        f4 a = zero4;
#pragma unroll
        for (int st = 0; st < 6; ++st) a = MFMA16(wt[st], xf[g][st], a, 0, 0, 0);
        if (nf < 12) {
          int h = nf < 6 ? nf : nf - 6;
          _Float16* dst = (nf < 6 ? qp_ : kp_) +
                          ((size_t)(b * NH_ + h) * 32 + t2_[g]) * 512 +
                          lane * 8 + (g & 1) * 4;
          h4 hv = {(_Float16)a[0], (_Float16)a[1], (_Float16)a[2], (_Float16)a[3]};
          *(h4*)dst = hv;
        } else {
          int hb = nf - 12;
          _Float16* vbase = vp_ + ((size_t)(b * NH_ + hb) * 32 + t2_[g]) * 512;
          int jb = (lr & 3) + (g & 1) * 4;
          int lgp = lr >> 2;
#pragma unroll
          for (int r = 0; r < 4; ++r)
            vbase[(lgp * 16 + lg * 4 + r) * 8 + jb] = (_Float16)a[r];
        }
      }
    }
  }
#undef XSH
#undef OSH
#undef HSP
#undef LNS
#undef XP
}

extern "C" void kernel_launch(void* const* d_in, const int* in_sizes, int n_in,
                              void* d_out, int out_size, void* d_ws, size_t ws_size,
                              hipStream_t stream) {
  const float* goals   = (const float*)d_in[0];
  const float* obss    = (const float*)d_in[1];
  const float* w_go    = (const float*)d_in[2];
  const float* b_go    = (const float*)d_in[3];
  const float* pos_emb = (const float*)d_in[4];
  const float* wq      = (const float*)d_in[5];
  const float* wk      = (const float*)d_in[6];
  const float* wv      = (const float*)d_in[7];
  const float* w_proj  = (const float*)d_in[8];
  const float* b_proj  = (const float*)d_in[9];
  const float* ln1_g   = (const float*)d_in[10];
  const float* ln1_b   = (const float*)d_in[11];
  const float* ln2_g   = (const float*)d_in[12];
  const float* ln2_b   = (const float*)d_in[13];
  const float* w_ff1   = (const float*)d_in[14];
  const float* b_ff1   = (const float*)d_in[15];
  const float* w_ff2   = (const float*)d_in[16];
  const float* b_ff2   = (const float*)d_in[17];
  const float* lnf_g   = (const float*)d_in[18];
  const float* lnf_b   = (const float*)d_in[19];
  const float* w_act   = (const float*)d_in[20];
  const float* b_act   = (const float*)d_in[21];
  float* out = (float*)d_out;

  const int M = B_ * T_;  // 16384
  float* ws = (float*)d_ws;
  size_t off = 0;
  _Float16* P = (_Float16*)(ws + off); off += PACK_TOTAL / 2 + 64;
  float* x = ws + off; off += (size_t)M * 96;
  _Float16* Qb[2]; _Float16* Kb[2]; _Float16* Vb[2];
  for (int p = 0; p < 2; ++p) {
    Qb[p] = (_Float16*)(ws + off); off += (size_t)M * 48;
    Kb[p] = (_Float16*)(ws + off); off += (size_t)M * 48;
    Vb[p] = (_Float16*)(ws + off); off += (size_t)M * 48;
  }

  pack_all_kernel<<<(PACK_TOTAL + 255) / 256, 256, 0, stream>>>(
      w_go, wq, wk, wv, w_proj, w_ff1, w_ff2, w_act, P);

  embed_kernel<<<256, 384, 0, stream>>>(
      goals, obss, pos_emb, b_go, P + OFF_GO, x, ln1_g, ln1_b,
      P + OFF_QKV, Qb[0], Kb[0], Vb[0]);

  for (int l = 0; l < L_; ++l) {
    int sp = l & 1, dp = (l + 1) & 1;
    if (l < L_ - 1) {
      layer_kernel<false><<<256, 384, 0, stream>>>(
          Qb[sp], Kb[sp], Vb[sp],
          P + OFF_PROJ + (size_t)l * 9216, b_proj + l * 96, x,
          P + OFF_FF1 + (size_t)l * 36864, b_ff1 + l * 384,
          P + OFF_FF2 + (size_t)l * 36864, b_ff2 + l * 96,
          ln2_g + l * 96, ln2_b + l * 96,
          ln1_g + (l + 1) * 96, ln1_b + (l + 1) * 96,
          P + OFF_QKV + (size_t)(l + 1) * 27648, nullptr,
          Qb[dp], Kb[dp], Vb[dp], nullptr);
    } else {
      layer_kernel<true><<<256, 384, 0, stream>>>(
          Qb[sp], Kb[sp], Vb[sp],
          P + OFF_PROJ + (size_t)l * 9216, b_proj + l * 96, x,
          P + OFF_FF1 + (size_t)l * 36864, b_ff1 + l * 384,
          P + OFF_FF2 + (size_t)l * 36864, b_ff2 + l * 96,
          ln2_g + l * 96, ln2_b + l * 96,
          lnf_g, lnf_b, P + OFF_ACT, b_act,
          nullptr, nullptr, nullptr, out);
    }
  }
}